// Round 3
// baseline (90.416 us; speedup 1.0000x reference)
//
#include <hip/hip_runtime.h>
#include <math.h>

#define RES   64
#define NPTS  (RES * RES)   // 4096 grid points
#define NB    4             // batches
#define NN    128           // components per batch
#define NP    16            // points per component
#define STRIDE 36           // padded floats per comp in LDS (144 B, 16B-aligned;
                            // wave's 8 concurrent b128 ops -> 8 distinct bank groups)
#define PTS_PER_BLK 32      // half a grid row (uniform x0)

// ---------------------------------------------------------------------------
// One launch, 512 blocks x 1024 threads (16 waves/block, 2 blocks/CU =
// 8 waves/SIMD). R2 was LDS-pipe-bound (~25 ds_read_b128/thread). This
// version: B lives in registers (8 x float4 from global, 8-lane broadcast,
// L1-resident 16 KB/batch); only D staged in LDS; w2 stays in registers via
// full butterfly broadcast (no sW2 array, one barrier removed); psum write
// is a single b128. LDS ops/thread ~29 -> ~11.
// ---------------------------------------------------------------------------
__global__ __launch_bounds__(1024, 8)
void fused_kernel(const float* __restrict__ Bs, const float* __restrict__ Ds,
                  float* __restrict__ out) {
    __shared__ __align__(16) float sD[NN * STRIDE];      // 18 KB
    __shared__ __align__(16) float psum[NN * STRIDE];    // 18 KB (rows use [0,32))
    __shared__ float pp[8][PTS_PER_BLK + 1];             // 1 KB

    const int bid  = blockIdx.x;
    const int b    = bid >> 7;          // batch
    const int pblk = bid & 127;         // 32-point block (half grid row)
    const int t    = threadIdx.x;       // 0..1023

    const int n   = t >> 3;             // component 0..127
    const int sub = t & 7;              // j-pair in w2 phase / point-group in main

    // ---- B -> registers straight from global (no LDS round-trip).
    // 8 lanes of a comp read the same 16B line -> broadcast; issued first so
    // the latency hides under the D-staging barrier.
    float4 Br[8];
    {
        const float4* gB = (const float4*)(Bs + (size_t)b * NN * NP * 2)
                         + (size_t)n * 8;
        #pragma unroll
        for (int q = 0; q < 8; ++q) Br[q] = gB[q];
    }
    // ---- stage D -> LDS (padded layout): exactly 1 float4 per thread ----
    {
        const float4* gD = (const float4*)(Ds + (size_t)b * NN * NP * 2);
        const int off = (t >> 3) * STRIDE + (t & 7) * 4;
        *(float4*)(sD + off) = gD[t];
    }
    __syncthreads();

    const float4* D4 = (const float4*)(sD + n * STRIDE);

    // ---- w2: 8 threads/comp, thread owns d-pairs {2*sub, 2*sub+1}.
    // relu(min)==min then max-with-0 init (monotone commute). Butterfly
    // leaves the full max in ALL 8 lanes -> w2 stays in a register.
    float w2n;
    {
        const float4 fd = D4[sub];      // (d0[2s], d1[2s], d0[2s+1], d1[2s+1])
        float w = 0.0f;
        #pragma unroll
        for (int q = 0; q < 8; ++q) {
            const float4 fb = Br[q];    // (b0[2q], b1[2q], b0[2q+1], b1[2q+1])
            w = fmaxf(w, fminf(fd.x - fb.x, fd.y - fb.y));
            w = fmaxf(w, fminf(fd.x - fb.z, fd.y - fb.w));
            w = fmaxf(w, fminf(fd.z - fb.x, fd.w - fb.y));
            w = fmaxf(w, fminf(fd.z - fb.z, fd.w - fb.w));
        }
        w = fmaxf(w, __shfl_xor(w, 1));
        w = fmaxf(w, __shfl_xor(w, 2));
        w = fmaxf(w, __shfl_xor(w, 4));
        if (!isfinite(w)) w = 0.0f;
        w2n = w * w;
    }

    // ---- main loop: comp n (B in regs, D from LDS) vs 4 grid points ----
    const int p0 = pblk * PTS_PER_BLK + 4 * sub;
    const int i0 = p0 >> 6;             // block-uniform row -> uniform x0
    const float x0 = -3.0f + 6.0f * (float)i0 / 63.0f;
    float x1v[4];
    #pragma unroll
    for (int j = 0; j < 4; ++j)
        x1v[j] = -3.0f + 6.0f * (float)((p0 + j) & 63) / 63.0f;

    float db[4] = {1e30f, 1e30f, 1e30f, 1e30f};
    float dd[4] = {1e30f, 1e30f, 1e30f, 1e30f};
    #pragma unroll 4
    for (int q = 0; q < 8; ++q) {       // 2 boundary points per float4
        const float4 fb = Br[q];        // registers
        const float4 fd = D4[q];        // LDS, 8-lane broadcast, conflict-free
        float s  = fb.x - x0;           // shared across the 4 grid points
        float sd = x0 - fd.x;
        #pragma unroll
        for (int j = 0; j < 4; ++j) {
            db[j] = fminf(db[j], fmaxf(s,  fb.y - x1v[j]));
            dd[j] = fminf(dd[j], fmaxf(sd, x1v[j] - fd.y));
        }
        s  = fb.z - x0;
        sd = x0 - fd.z;
        #pragma unroll
        for (int j = 0; j < 4; ++j) {
            db[j] = fminf(db[j], fmaxf(s,  fb.w - x1v[j]));
            dd[j] = fminf(dd[j], fmaxf(sd, x1v[j] - fd.w));
        }
    }

    const float cexp = -0.5f / (0.3f * 0.3f);
    float4 kv;
    {
        float r;
        r = fmaxf(fmaxf(db[0], dd[0]), 0.0f); kv.x = __expf(cexp * r * r) * w2n;
        r = fmaxf(fmaxf(db[1], dd[1]), 0.0f); kv.y = __expf(cexp * r * r) * w2n;
        r = fmaxf(fmaxf(db[2], dd[2]), 0.0f); kv.z = __expf(cexp * r * r) * w2n;
        r = fmaxf(fmaxf(db[3], dd[3]), 0.0f); kv.w = __expf(cexp * r * r) * w2n;
    }
    // single b128 store; stride 36 -> same conflict-free bank walk as staging
    *(float4*)(psum + n * STRIDE + 4 * sub) = kv;
    __syncthreads();

    // ---- reduction: 32 points x sum over 128 comps, two LDS stages ----
    if (t < 256) {                      // oct = t>>5 owns 16 comps for point p
        const int p   = t & 31;
        const int oct = t >> 5;
        float s = 0.0f;
        #pragma unroll
        for (int m = 0; m < 16; ++m)    // bank (4m+p)%32: 2 lanes/bank = free
            s += psum[(oct * 16 + m) * STRIDE + p];
        pp[oct][p] = s;
    }
    __syncthreads();
    if (t < PTS_PER_BLK) {
        float s = 0.0f;
        #pragma unroll
        for (int q = 0; q < 8; ++q) s += pp[q][t];
        out[(size_t)b * NPTS + pblk * PTS_PER_BLK + t] = s;
    }
}

extern "C" void kernel_launch(void* const* d_in, const int* in_sizes, int n_in,
                              void* d_out, int out_size, void* d_ws, size_t ws_size,
                              hipStream_t stream) {
    const float* Bs = (const float*)d_in[0];
    const float* Ds = (const float*)d_in[1];
    float* out = (float*)d_out;
    fused_kernel<<<dim3(NB * 128), dim3(1024), 0, stream>>>(Bs, Ds, out);
}

// Round 4
// 61.526 us; speedup vs baseline: 1.4696x; 1.4696x over previous
//
#include <hip/hip_runtime.h>
#include <math.h>

#define RES   64
#define NPTS  (RES * RES)   // 4096 grid points
#define NB    4             // batches
#define NN    128           // components per batch
#define NP    16            // points per component
#define STRIDE 36           // padded floats per comp in LDS (144 B, 16B-aligned;
                            // wave's 8 concurrent b128 reads -> 8 distinct bank groups)
#define PTS_PER_BLK 32      // half a grid row (uniform x0)

// ---------------------------------------------------------------------------
// ONE launch, 512 blocks x 1024 threads (16 waves/block, 2 blocks/CU =
// 8 waves/SIMD). Best measured config (61.95 us). B and D both staged to
// LDS exactly once per block (coalesced, no HBM contention with the
// harness's concurrent poison-fill — R3 showed per-thread global B loads
// slow the fill from 6.8 to 5.5 TB/s and cost +28 us). w2 computed
// in-block with 8 threads/comp + shfl butterfly; its barrier cost hides
// behind the main db/dd loop.
// ---------------------------------------------------------------------------
__global__ __launch_bounds__(1024, 8)
void fused_kernel(const float* __restrict__ Bs, const float* __restrict__ Ds,
                  float* __restrict__ out) {
    __shared__ __align__(16) float sB[NN * STRIDE];      // 18 KB
    __shared__ __align__(16) float sD[NN * STRIDE];      // 18 KB
    __shared__ float sW2[NN];                            // 0.5 KB
    __shared__ float psum[NN][PTS_PER_BLK + 1];          // 16.5 KB, +1 pad
    __shared__ float pp[8][PTS_PER_BLK + 1];             // 1 KB

    const int bid  = blockIdx.x;
    const int b    = bid >> 7;          // batch
    const int pblk = bid & 127;         // 32-point block (half grid row)
    const int t    = threadIdx.x;       // 0..1023

    // ---- stage global -> LDS: 1024 float4 per array, exactly 1 per thread ----
    {
        const float4* gB = (const float4*)(Bs + (size_t)b * NN * NP * 2);
        const float4* gD = (const float4*)(Ds + (size_t)b * NN * NP * 2);
        const int off = (t >> 3) * STRIDE + (t & 7) * 4;   // padded, 16B-aligned
        *(float4*)(sB + off) = gB[t];
        *(float4*)(sD + off) = gD[t];
    }
    __syncthreads();

    const int n   = t >> 3;             // component 0..127
    const int sub = t & 7;              // 0..7 (j-pair in w2 phase, point-group in main)

    const float4* B4 = (const float4*)(sB + n * STRIDE);
    const float4* D4 = (const float4*)(sD + n * STRIDE);

    // ---- w2 phase: 8 threads/comp, thread owns j = {2*sub, 2*sub+1} ----
    // relu(min) == min then max-with-0 init (monotone commute).
    {
        const float4 fd = D4[sub];      // (d0[2s], d1[2s], d0[2s+1], d1[2s+1])
        float w = 0.0f;
        #pragma unroll
        for (int q = 0; q < 8; ++q) {
            const float4 fb = B4[q];    // (b0[2q], b1[2q], b0[2q+1], b1[2q+1])
            w = fmaxf(w, fminf(fd.x - fb.x, fd.y - fb.y));
            w = fmaxf(w, fminf(fd.x - fb.z, fd.y - fb.w));
            w = fmaxf(w, fminf(fd.z - fb.x, fd.w - fb.y));
            w = fmaxf(w, fminf(fd.z - fb.z, fd.w - fb.w));
        }
        // reduce across the 8 sub-lanes (contiguous lanes within the wave)
        w = fmaxf(w, __shfl_xor(w, 1));
        w = fmaxf(w, __shfl_xor(w, 2));
        w = fmaxf(w, __shfl_xor(w, 4));
        if (sub == 0) {
            if (!isfinite(w)) w = 0.0f;
            sW2[n] = w * w;
        }
    }
    // NO barrier here: sW2 is only read after the barrier that follows the
    // main db/dd loop below -> the sync cost hides behind ~450 VALU ops.

    // ---- main loop: this thread's comp n vs its 4 grid points ----
    const int p0 = pblk * PTS_PER_BLK + 4 * sub;
    const int i0 = p0 >> 6;             // block-uniform row -> uniform x0
    const float x0 = -3.0f + 6.0f * (float)i0 / 63.0f;
    float x1v[4];
    #pragma unroll
    for (int j = 0; j < 4; ++j)
        x1v[j] = -3.0f + 6.0f * (float)((p0 + j) & 63) / 63.0f;

    // wave: n = lane>>3 -> 8 distinct comps, 8-lane broadcast; comp stride
    // 144 B -> bank groups 0,4,...,28: conflict-free b128 reads.
    float db[4] = {1e30f, 1e30f, 1e30f, 1e30f};
    float dd[4] = {1e30f, 1e30f, 1e30f, 1e30f};
    #pragma unroll 4
    for (int q = 0; q < 8; ++q) {       // 2 boundary points per float4
        const float4 fb = B4[q];
        const float4 fd = D4[q];
        float s  = fb.x - x0;           // shared across the 4 grid points
        float sd = x0 - fd.x;
        #pragma unroll
        for (int j = 0; j < 4; ++j) {
            db[j] = fminf(db[j], fmaxf(s,  fb.y - x1v[j]));
            dd[j] = fminf(dd[j], fmaxf(sd, x1v[j] - fd.y));
        }
        s  = fb.z - x0;
        sd = x0 - fd.z;
        #pragma unroll
        for (int j = 0; j < 4; ++j) {
            db[j] = fminf(db[j], fmaxf(s,  fb.w - x1v[j]));
            dd[j] = fminf(dd[j], fmaxf(sd, x1v[j] - fd.w));
        }
    }

    __syncthreads();                    // sW2 visibility (write was pre-loop)
    const float w2n = sW2[n];           // 8-lane broadcast
    const float cexp = -0.5f / (0.3f * 0.3f);
    #pragma unroll
    for (int j = 0; j < 4; ++j) {
        const float r = fmaxf(fmaxf(db[j], dd[j]), 0.0f);
        // scalar stores, pad 33: exactly 2 lanes/bank = wave64 minimum (free)
        psum[n][4 * sub + j] = __expf(cexp * r * r) * w2n;
    }
    __syncthreads();

    // ---- reduction: 32 points x sum over 128 comps, two LDS stages ----
    if (t < 256) {                      // oct = t>>5 owns 16 comps for point p
        const int p   = t & 31;
        const int oct = t >> 5;
        float s = 0.0f;
        #pragma unroll
        for (int m = 0; m < 16; ++m)    // addr ≡ oct*16+m+p (mod 32): ≤2-way, free
            s += psum[oct * 16 + m][p];
        pp[oct][p] = s;
    }
    __syncthreads();
    if (t < PTS_PER_BLK) {
        float s = 0.0f;
        #pragma unroll
        for (int q = 0; q < 8; ++q) s += pp[q][t];
        out[(size_t)b * NPTS + pblk * PTS_PER_BLK + t] = s;
    }
}

extern "C" void kernel_launch(void* const* d_in, const int* in_sizes, int n_in,
                              void* d_out, int out_size, void* d_ws, size_t ws_size,
                              hipStream_t stream) {
    const float* Bs = (const float*)d_in[0];
    const float* Ds = (const float*)d_in[1];
    float* out = (float*)d_out;
    fused_kernel<<<dim3(NB * 128), dim3(1024), 0, stream>>>(Bs, Ds, out);
}